// Round 13
// baseline (319.793 us; speedup 1.0000x reference)
//
#include <hip/hip_runtime.h>

#define N_NODES 30000
#define N_EDGES 300000
#define N_TRIP 200000
#define NUM_RELS 8
#define F_RAW 128
#define DDIM 256

#define NBUCK (2 * NUM_RELS * N_NODES)                    // 480000 buckets
#define SCAN_CHUNK 1024
#define NCHUNK ((NBUCK + SCAN_CHUNK - 1) / SCAN_CHUNK)    // 469
#define NPAD (NCHUNK * SCAN_CHUNK)                        // 480256

#define KBIG 2304   // 8 rel blocks + x block
#define KBWD 2048   // 8 rel blocks

// fused-prep segment sizes
#define FB_N (N_NODES * F_RAW)   // 3,840,000
#define WTA_N (F_RAW * DDIM)     // 32,768
#define WC1_N (256 * KBIG)       // 589,824
#define WC2_N (256 * KBWD)       // 524,288
#define PREP_TOTAL (FB_N + WTA_N + WC1_N + WC2_N + NPAD)

typedef __attribute__((ext_vector_type(8))) short short8;
typedef __attribute__((ext_vector_type(8))) unsigned short u16x8;
typedef __attribute__((ext_vector_type(4))) float f32x4;

__device__ inline unsigned short f2bf(float f) {
  unsigned u = __builtin_bit_cast(unsigned, f);
  u = (u + 0x7FFFu + ((u >> 16) & 1u)) >> 16;
  return (unsigned short)u;
}
__device__ inline float bf2f(unsigned short s) {
  unsigned u = ((unsigned)s) << 16;
  return __builtin_bit_cast(float, u);
}

// ===========================================================================
// Fused prep: feats->bf16, Wta transpose, Wcat1/Wcat2 build, cnt zero.
// ===========================================================================
__global__ void prep_kernel(const float* __restrict__ feats,
                            const float* __restrict__ W_affine,
                            const float* __restrict__ Wf,
                            const float* __restrict__ Wb,
                            const float* __restrict__ Wl,
                            unsigned short* __restrict__ fb,
                            unsigned short* __restrict__ Wta,
                            unsigned short* __restrict__ Wcat1,
                            unsigned short* __restrict__ Wcat2,
                            int* __restrict__ cnt) {
  int i = blockIdx.x * blockDim.x + threadIdx.x;
  if (i < FB_N) {
    fb[i] = f2bf(feats[i]);
    return;
  }
  i -= FB_N;
  if (i < WTA_N) {  // Wta[n][k] = W_affine[k][n]
    const int n = i >> 7, k = i & 127;
    Wta[i] = f2bf(W_affine[(size_t)k * DDIM + n]);
    return;
  }
  i -= WTA_N;
  if (i < WC1_N) {  // Wcat1[n][kk]: kk<2048 Wf[kk>>8][kk&255][n] else Wl
    const int n = i / KBIG, kk = i - n * KBIG;
    float v;
    if (kk < 2048) {
      const int r = kk >> 8, k = kk & 255;
      v = Wf[((size_t)r * 256 + k) * 256 + n];
    } else {
      v = Wl[(size_t)(kk - 2048) * 256 + n];
    }
    Wcat1[i] = f2bf(v);
    return;
  }
  i -= WC1_N;
  if (i < WC2_N) {  // Wcat2[n][kk] = Wb[kk>>8][kk&255][n]
    const int n = i / KBWD, kk = i - n * KBWD;
    const int r = kk >> 8, k = kk & 255;
    Wcat2[i] = f2bf(Wb[((size_t)r * 256 + k) * 256 + n]);
    return;
  }
  i -= WC2_N;
  if (i < NPAD) cnt[i] = 0;
}

// ===========================================================================
// Edge bucketing: counting sort by (rel, endpoint), both directions.
// fwd key = r*N + dst; bwd key = (8+r)*N + src. gidx[pos] = gather-node.
// ===========================================================================
__global__ void hist_kernel(const int* __restrict__ src,
                            const int* __restrict__ dst,
                            const int* __restrict__ et, int* __restrict__ cnt) {
  int e = blockIdx.x * blockDim.x + threadIdx.x;
  if (e >= N_EDGES) return;
  int r = et[e];
  atomicAdd(&cnt[r * N_NODES + dst[e]], 1);
  atomicAdd(&cnt[(NUM_RELS + r) * N_NODES + src[e]], 1);
}

__global__ __launch_bounds__(256) void scan1_kernel(const int* __restrict__ cnt,
                                                    int* __restrict__ offs,
                                                    int* __restrict__ bsum) {
  __shared__ int s[256];
  const int b = blockIdx.x, t = threadIdx.x;
  const int base = b * SCAN_CHUNK + t * 4;
  int4 v = *reinterpret_cast<const int4*>(&cnt[base]);
  int tsum = v.x + v.y + v.z + v.w;
  s[t] = tsum;
  __syncthreads();
  for (int off = 1; off < 256; off <<= 1) {
    int x = (t >= off) ? s[t - off] : 0;
    __syncthreads();
    s[t] += x;
    __syncthreads();
  }
  int excl = s[t] - tsum;
  offs[base + 0] = excl;
  offs[base + 1] = excl + v.x;
  offs[base + 2] = excl + v.x + v.y;
  offs[base + 3] = excl + v.x + v.y + v.z;
  if (t == 0) bsum[b] = s[255];
}

__global__ __launch_bounds__(512) void scan2_kernel(int* __restrict__ bsum) {
  __shared__ int s[512];
  const int t = threadIdx.x;
  int v = (t < NCHUNK) ? bsum[t] : 0;
  s[t] = v;
  __syncthreads();
  for (int off = 1; off < 512; off <<= 1) {
    int x = (t >= off) ? s[t - off] : 0;
    __syncthreads();
    s[t] += x;
    __syncthreads();
  }
  if (t < NCHUNK) bsum[t] = s[t] - v;
}

__global__ void scan3_kernel(int* __restrict__ offs,
                             const int* __restrict__ bsum,
                             int* __restrict__ cur) {
  int i = blockIdx.x * blockDim.x + threadIdx.x;
  if (i >= NPAD) return;
  int v = offs[i] + bsum[i / SCAN_CHUNK];
  offs[i] = v;
  if (i < NBUCK) cur[i] = v;
}

__global__ void fill_kernel(const int* __restrict__ src,
                            const int* __restrict__ dst,
                            const int* __restrict__ et, int* __restrict__ cur,
                            int* __restrict__ gidx) {
  int e = blockIdx.x * blockDim.x + threadIdx.x;
  if (e >= N_EDGES) return;
  int r = et[e];
  int s = src[e], d = dst[e];
  int p1 = atomicAdd(&cur[r * N_NODES + d], 1);
  gidx[p1] = s;  // fwd: gather src, owner dst
  int p2 = atomicAdd(&cur[(NUM_RELS + r) * N_NODES + s], 1);
  gidx[p2] = d;  // bwd: gather dst, owner src
}

// ===========================================================================
// Affine GEMM (proven 128x128): C_bf16[M, ldc] = A[M,lda(K)] @ Bt[256,K]^T + b
// ===========================================================================
__global__ __launch_bounds__(256) void gemm128_kernel(
    const unsigned short* __restrict__ A, int lda, int K,
    const unsigned short* __restrict__ Bt, const float* __restrict__ bias,
    unsigned short* __restrict__ Cb, int ldc, int M) {
  __shared__ __align__(16) unsigned short As[128 * 64];
  __shared__ __align__(16) unsigned short Bs[128 * 64];

  const int tid = threadIdx.x;
  const int lane = tid & 63;
  const int wave = tid >> 6;
  const int bm = blockIdx.y * 128;
  const int bn = blockIdx.x * 128;
  const int wr = wave >> 1;
  const int wc = wave & 1;
  const int g = lane >> 4;
  const int rl = lane & 15;

  f32x4 acc[4][4];
#pragma unroll
  for (int i = 0; i < 4; ++i)
#pragma unroll
    for (int j = 0; j < 4; ++j) acc[i][j] = (f32x4){0.f, 0.f, 0.f, 0.f};

  for (int k0 = 0; k0 < K; k0 += 64) {
#pragma unroll
    for (int c = 0; c < 8; ++c) {
      const int chunk = c * 4 + wave;
      if (chunk < 16) {
        const int S = chunk * 64 + lane;
        const int row = S >> 3;
        const int s = S & 7;
        int grow = bm + row;
        if (grow > M - 1) grow = M - 1;
        const int kcol = k0 + ((s ^ (row & 7)) << 3);
        const unsigned short* gp = A + (size_t)grow * lda + kcol;
        unsigned short* lp = As + (size_t)chunk * 512;
        __builtin_amdgcn_global_load_lds(
            (const __attribute__((address_space(1))) void*)gp,
            (__attribute__((address_space(3))) void*)lp, 16, 0, 0);
      } else {
        const int S = (chunk - 16) * 64 + lane;
        const int row = S >> 3;
        const int s = S & 7;
        const int kcol = k0 + ((s ^ (row & 7)) << 3);
        const unsigned short* gp = Bt + (size_t)(bn + row) * K + kcol;
        unsigned short* lp = Bs + (size_t)(chunk - 16) * 512;
        __builtin_amdgcn_global_load_lds(
            (const __attribute__((address_space(1))) void*)gp,
            (__attribute__((address_space(3))) void*)lp, 16, 0, 0);
      }
    }
    __syncthreads();

#pragma unroll
    for (int kk = 0; kk < 2; ++kk) {
      short8 a[4], b[4];
#pragma unroll
      for (int mi = 0; mi < 4; ++mi) {
        const int row = wr * 64 + mi * 16 + rl;
        const int slot = (kk * 4 + g) ^ (row & 7);
        a[mi] = *(const short8*)&As[row * 64 + slot * 8];
      }
#pragma unroll
      for (int ni = 0; ni < 4; ++ni) {
        const int row = wc * 64 + ni * 16 + rl;
        const int slot = (kk * 4 + g) ^ (row & 7);
        b[ni] = *(const short8*)&Bs[row * 64 + slot * 8];
      }
#pragma unroll
      for (int mi = 0; mi < 4; ++mi)
#pragma unroll
        for (int ni = 0; ni < 4; ++ni)
          acc[mi][ni] = __builtin_amdgcn_mfma_f32_16x16x32_bf16(
              a[mi], b[ni], acc[mi][ni], 0, 0, 0);
    }
    __syncthreads();
  }

#pragma unroll
  for (int mi = 0; mi < 4; ++mi) {
#pragma unroll
    for (int j = 0; j < 4; ++j) {
      const int row = bm + wr * 64 + mi * 16 + g * 4 + j;
      if (row >= M) continue;
#pragma unroll
      for (int ni = 0; ni < 4; ++ni) {
        const int col = bn + wc * 64 + ni * 16 + rl;
        Cb[(size_t)row * ldc + col] = f2bf(acc[mi][ni][j] + bias[col]);
      }
    }
  }
}

// ===========================================================================
// Wide-K GEMM, BM=64 x BN=128, 2-PHASE double-buffered staging:
// issue STAGE(t+1) before ds_read+MFMA of tile t; raw s_barrier + vmcnt(0)
// only at iteration top, so next-tile loads stay in flight across the
// barrier (latency hidden under compute). 48 KB LDS (2 buffers).
// OUT_MODE: 0 = write f32; 2 = f32-RMW + bf16 copy.
// ===========================================================================
template <int OUT_MODE>
__global__ __launch_bounds__(256) void gemm64_kernel(
    const unsigned short* __restrict__ A, int lda, int K,
    const unsigned short* __restrict__ Bt, float* __restrict__ Cf,
    unsigned short* __restrict__ Cb, int ldc, int M, int nblk) {
  __shared__ __align__(16) unsigned short As[2][64 * 64];   // 16 KB
  __shared__ __align__(16) unsigned short Bs[2][128 * 64];  // 32 KB

  const int tid = threadIdx.x;
  const int lane = tid & 63;
  const int wave = tid >> 6;

  // bijective XCD swizzle (nblk % 8 != 0 safe)
  const int orig = blockIdx.x;
  const int q = nblk >> 3, r = nblk & 7;
  const int xcd = orig & 7, off = orig >> 3;
  const int wg =
      (xcd < r) ? xcd * (q + 1) + off : r * (q + 1) + (xcd - r) * q + off;
  const int bm = (wg >> 1) * 64;
  const int bn = (wg & 1) * 128;

  const int wr = wave >> 1;  // 0..1: 32-row half
  const int wc = wave & 1;   // 0..1: 64-col half
  const int g = lane >> 4;
  const int rl = lane & 15;

  f32x4 acc[2][4];
#pragma unroll
  for (int i = 0; i < 2; ++i)
#pragma unroll
    for (int j = 0; j < 4; ++j) acc[i][j] = (f32x4){0.f, 0.f, 0.f, 0.f};

  // stage one 64-wide k-tile into buffer `buf` (6 gload_lds chunks per wave)
  auto stage = [&](int buf, int k0) {
#pragma unroll
    for (int c = 0; c < 6; ++c) {
      const int chunk = c * 4 + wave;
      if (chunk < 8) {
        const int S = chunk * 64 + lane;
        const int row = S >> 3;  // 0..63
        const int s = S & 7;
        int grow = bm + row;
        if (grow > M - 1) grow = M - 1;
        const unsigned short* gp =
            A + (size_t)grow * lda + k0 + ((s ^ (row & 7)) << 3);
        unsigned short* lp = &As[buf][0] + (size_t)chunk * 512;
        __builtin_amdgcn_global_load_lds(
            (const __attribute__((address_space(1))) void*)gp,
            (__attribute__((address_space(3))) void*)lp, 16, 0, 0);
      } else {
        const int S = (chunk - 8) * 64 + lane;
        const int row = S >> 3;  // 0..127
        const int s = S & 7;
        const unsigned short* gp =
            Bt + (size_t)(bn + row) * K + k0 + ((s ^ (row & 7)) << 3);
        unsigned short* lp = &Bs[buf][0] + (size_t)(chunk - 8) * 512;
        __builtin_amdgcn_global_load_lds(
            (const __attribute__((address_space(1))) void*)gp,
            (__attribute__((address_space(3))) void*)lp, 16, 0, 0);
      }
    }
  };

  const int nt = K >> 6;
  stage(0, 0);
  for (int t = 0; t < nt; ++t) {
    // wait for THIS tile's loads (only outstanding ops at loop top), then
    // barrier: all waves' tile-t chunks are in LDS. Next-tile loads issued
    // below stay in flight across the next barrier.
    asm volatile("s_waitcnt vmcnt(0)" ::: "memory");
    __builtin_amdgcn_s_barrier();
    if (t + 1 < nt) stage((t + 1) & 1, (t + 1) << 6);

    const unsigned short* Asc = &As[t & 1][0];
    const unsigned short* Bsc = &Bs[t & 1][0];
#pragma unroll
    for (int kk = 0; kk < 2; ++kk) {
      short8 a[2], b[4];
#pragma unroll
      for (int mi = 0; mi < 2; ++mi) {
        const int row = wr * 32 + mi * 16 + rl;
        const int slot = (kk * 4 + g) ^ (row & 7);
        a[mi] = *(const short8*)&Asc[row * 64 + slot * 8];
      }
#pragma unroll
      for (int ni = 0; ni < 4; ++ni) {
        const int row = wc * 64 + ni * 16 + rl;
        const int slot = (kk * 4 + g) ^ (row & 7);
        b[ni] = *(const short8*)&Bsc[row * 64 + slot * 8];
      }
#pragma unroll
      for (int mi = 0; mi < 2; ++mi)
#pragma unroll
        for (int ni = 0; ni < 4; ++ni)
          acc[mi][ni] = __builtin_amdgcn_mfma_f32_16x16x32_bf16(
              a[mi], b[ni], acc[mi][ni], 0, 0, 0);
    }
    // no trailing barrier: a wave reaches the next top-barrier only after
    // its tile-t ds_reads were consumed by MFMA issue; buffer t&1 is not
    // overwritten until iteration t+2's stage, which is after that barrier.
  }

#pragma unroll
  for (int mi = 0; mi < 2; ++mi) {
#pragma unroll
    for (int j = 0; j < 4; ++j) {
      const int row = bm + wr * 32 + mi * 16 + g * 4 + j;
      if (row >= M) continue;
#pragma unroll
      for (int ni = 0; ni < 4; ++ni) {
        const int col = bn + wc * 64 + ni * 16 + rl;
        float v = acc[mi][ni][j];
        const size_t idx = (size_t)row * ldc + col;
        if (OUT_MODE == 0) {
          Cf[idx] = v;
        } else {
          v += Cf[idx];
          Cf[idx] = v;
          Cb[idx] = f2bf(v);
        }
      }
    }
  }
}

// ===========================================================================
// z-gather (32-lane rows): 2 buckets per wave, 16 B/lane loads, 4-deep batch.
// ===========================================================================
__global__ __launch_bounds__(256) void zgatherw_kernel(
    unsigned short* __restrict__ Z, int colbase,
    const int* __restrict__ offs_base, const int* __restrict__ gidx) {
  const int lane = threadIdx.x & 63;
  const int hl = lane >> 5;
  const int l5 = lane & 31;
  const int b = blockIdx.x * 8 + (threadIdx.x >> 6) * 2 + hl;
  if (b >= NUM_RELS * N_NODES) return;
  const int r = b / N_NODES;
  const int v = b - r * N_NODES;
  const int s = offs_base[b], e = offs_base[b + 1];

  float acc[8] = {};
  for (int i = s; i < e; i += 4) {
    int g4[4];
    u16x8 xs[4];
#pragma unroll
    for (int q = 0; q < 4; ++q)
      if (i + q < e) g4[q] = gidx[i + q];
#pragma unroll
    for (int q = 0; q < 4; ++q)
      if (i + q < e)
        xs[q] = *(const u16x8*)&Z[(size_t)g4[q] * KBIG + 2048 + l5 * 8];
#pragma unroll
    for (int q = 0; q < 4; ++q)
      if (i + q < e) {
#pragma unroll
        for (int j = 0; j < 8; ++j) acc[j] += bf2f((unsigned short)xs[q][j]);
      }
  }
  u16x8 o;
#pragma unroll
  for (int j = 0; j < 8; ++j) o[j] = (short)f2bf(acc[j]);
  *(u16x8*)&Z[(size_t)v * KBIG + colbase + r * 256 + l5 * 8] = o;
}

// ===========================================================================
// DistMult scoring (32-lane rows, bf16 h).
// ===========================================================================
__global__ __launch_bounds__(256) void score32_kernel(
    const unsigned short* __restrict__ hb, const float* __restrict__ wrel,
    const int* __restrict__ ts, const int* __restrict__ tr,
    const int* __restrict__ to, float* __restrict__ out, int T) {
  const int t = blockIdx.x * 8 + (threadIdx.x >> 5);
  if (t >= T) return;
  const int l5 = threadIdx.x & 31;
  const int s = ts[t];
  const int r = tr[t];
  const int o = to[t];
  const u16x8 hs = *(const u16x8*)&hb[(size_t)s * DDIM + l5 * 8];
  const u16x8 ho = *(const u16x8*)&hb[(size_t)o * DDIM + l5 * 8];
  const float4 w0 = *(const float4*)&wrel[(size_t)r * DDIM + l5 * 8];
  const float4 w1 = *(const float4*)&wrel[(size_t)r * DDIM + l5 * 8 + 4];
  float sum = bf2f((unsigned short)hs[0]) * w0.x * bf2f((unsigned short)ho[0]) +
              bf2f((unsigned short)hs[1]) * w0.y * bf2f((unsigned short)ho[1]) +
              bf2f((unsigned short)hs[2]) * w0.z * bf2f((unsigned short)ho[2]) +
              bf2f((unsigned short)hs[3]) * w0.w * bf2f((unsigned short)ho[3]) +
              bf2f((unsigned short)hs[4]) * w1.x * bf2f((unsigned short)ho[4]) +
              bf2f((unsigned short)hs[5]) * w1.y * bf2f((unsigned short)ho[5]) +
              bf2f((unsigned short)hs[6]) * w1.z * bf2f((unsigned short)ho[6]) +
              bf2f((unsigned short)hs[7]) * w1.w * bf2f((unsigned short)ho[7]);
#pragma unroll
  for (int off = 16; off; off >>= 1) sum += __shfl_down(sum, off, 32);
  if (l5 == 0) out[t] = sum;
}

// ===========================================================================
extern "C" void kernel_launch(void* const* d_in, const int* in_sizes, int n_in,
                              void* d_out, int out_size, void* d_ws,
                              size_t ws_size, hipStream_t stream) {
  const float* feats = (const float*)d_in[0];
  const float* W_affine = (const float*)d_in[1];
  const float* b_affine = (const float*)d_in[2];
  const float* W_fwd = (const float*)d_in[3];
  const float* W_bwd = (const float*)d_in[4];
  const float* W_loop = (const float*)d_in[5];
  const float* w_relation = (const float*)d_in[6];
  const int* src = (const int*)d_in[7];
  const int* dst = (const int*)d_in[8];
  const int* etype = (const int*)d_in[9];
  const int* trip_s = (const int*)d_in[10];
  const int* trip_r = (const int*)d_in[11];
  const int* trip_o = (const int*)d_in[12];

  float* out_w = (float*)d_out;  // [N_TRIP]
  float* h = out_w + N_TRIP;     // [N_NODES * D] fp32

  char* ws = (char*)d_ws;
  unsigned short* fb = (unsigned short*)(ws);                 // 7,680,000
  unsigned short* Z = (unsigned short*)(ws + 7680000);        // 138,240,000
  unsigned short* hbf = (unsigned short*)(ws + 145920000);    // 15,360,000
  unsigned short* Wta = (unsigned short*)(ws + 161280000);    // 65,536
  unsigned short* Wcat1 = (unsigned short*)(ws + 161345536);  // 1,179,648
  unsigned short* Wcat2 = (unsigned short*)(ws + 162525184);  // 1,048,576
  int* cnt = (int*)(ws + 163573760);                          // 1,921,024
  int* offs = (int*)(ws + 165494784);                         // 1,921,024
  int* cur = (int*)(ws + 167415808);                          // 1,921,024
  int* bsum = (int*)(ws + 169336832);                         // 2,048
  int* gidx = (int*)(ws + 169338880);                         // 2,400,000

  // ---- fused prep (conversions + weight builds + cnt zero) ----
  prep_kernel<<<(PREP_TOTAL + 255) / 256, 256, 0, stream>>>(
      feats, W_affine, W_fwd, W_bwd, W_loop, fb, Wta, Wcat1, Wcat2, cnt);

  // ---- edge bucketing ----
  hist_kernel<<<(N_EDGES + 255) / 256, 256, 0, stream>>>(src, dst, etype, cnt);
  scan1_kernel<<<NCHUNK, 256, 0, stream>>>(cnt, offs, bsum);
  scan2_kernel<<<1, 512, 0, stream>>>(bsum);
  scan3_kernel<<<(NPAD + 255) / 256, 256, 0, stream>>>(offs, bsum, cur);
  fill_kernel<<<(N_EDGES + 255) / 256, 256, 0, stream>>>(src, dst, etype, cur,
                                                         gidx);

  // ---- x -> Z cols [2048, 2304) ----
  const dim3 agrid(2, (N_NODES + 127) / 128);
  gemm128_kernel<<<agrid, 256, 0, stream>>>(fb, F_RAW, F_RAW, Wta, b_affine,
                                            Z + 2048, KBIG, N_NODES);

  const int nblk = 2 * ((N_NODES + 63) / 64);  // 938
  const int zgrid = (NUM_RELS * N_NODES + 7) / 8;

  // ---- Z_fwd cols [0,2048); h = [Z_fwd | x] @ [Wf ; Wl] ----
  zgatherw_kernel<<<zgrid, 256, 0, stream>>>(Z, 0, offs, gidx);
  gemm64_kernel<0><<<nblk, 256, 0, stream>>>(Z, KBIG, KBIG, Wcat1, h, nullptr,
                                             DDIM, N_NODES, nblk);
  // ---- Z_bwd overwrites cols [0,2048); h += Z_bwd @ [Wb], emit hbf ----
  zgatherw_kernel<<<zgrid, 256, 0, stream>>>(Z, 0, offs + NUM_RELS * N_NODES,
                                             gidx);
  gemm64_kernel<2><<<nblk, 256, 0, stream>>>(Z, KBIG, KBWD, Wcat2, h, hbf,
                                             DDIM, N_NODES, nblk);

  // ---- DistMult scoring ----
  score32_kernel<<<(N_TRIP + 7) / 8, 256, 0, stream>>>(
      hbf, w_relation, trip_s, trip_r, trip_o, out_w, N_TRIP);
}

// Round 14
// 297.263 us; speedup vs baseline: 1.0758x; 1.0758x over previous
//
#include <hip/hip_runtime.h>

#define N_NODES 30000
#define N_EDGES 300000
#define N_TRIP 200000
#define NUM_RELS 8
#define F_RAW 128
#define DDIM 256

#define NBUCK (2 * NUM_RELS * N_NODES)                    // 480000 buckets
#define SCAN_CHUNK 1024
#define NCHUNK ((NBUCK + SCAN_CHUNK - 1) / SCAN_CHUNK)    // 469
#define NPAD (NCHUNK * SCAN_CHUNK)                        // 480256

#define KMRG 4352          // 8 fwd + 8 bwd + x tail (17 phases x 256)
#define NZM 200000         // multi-bucket slot cap (actual ~170.5K, 89-sigma)
#define XB0 200000         // row ids [200000,230000) = xb rows
#define ZROW 230000        // shared zero row

// fused-prep segment sizes
#define FB_N (N_NODES * F_RAW)   // 3,840,000
#define WTA_N (F_RAW * DDIM)     // 32,768
#define WC_N (256 * KMRG)        // 1,114,112
#define PREP_TOTAL (FB_N + WTA_N + WC_N + NPAD + 256)

typedef __attribute__((ext_vector_type(8))) short short8;
typedef __attribute__((ext_vector_type(8))) unsigned short u16x8;
typedef __attribute__((ext_vector_type(4))) float f32x4;

__device__ inline unsigned short f2bf(float f) {
  unsigned u = __builtin_bit_cast(unsigned, f);
  u = (u + 0x7FFFu + ((u >> 16) & 1u)) >> 16;
  return (unsigned short)u;
}
__device__ inline float bf2f(unsigned short s) {
  unsigned u = ((unsigned)s) << 16;
  return __builtin_bit_cast(float, u);
}

// ===========================================================================
// Fused prep: feats->bf16, Wta transpose, Wcat build (17 phases), cnt zero,
// zero-row zero. One dispatch, disjoint flat-index segments.
// ===========================================================================
__global__ void prep_kernel(const float* __restrict__ feats,
                            const float* __restrict__ W_affine,
                            const float* __restrict__ Wf,
                            const float* __restrict__ Wb,
                            const float* __restrict__ Wl,
                            unsigned short* __restrict__ fb,
                            unsigned short* __restrict__ Wta,
                            unsigned short* __restrict__ Wcat,
                            int* __restrict__ cnt,
                            unsigned short* __restrict__ zrow) {
  int i = blockIdx.x * blockDim.x + threadIdx.x;
  if (i < FB_N) {
    fb[i] = f2bf(feats[i]);
    return;
  }
  i -= FB_N;
  if (i < WTA_N) {  // Wta[n][k] = W_affine[k][n]
    const int n = i >> 7, k = i & 127;
    Wta[i] = f2bf(W_affine[(size_t)k * DDIM + n]);
    return;
  }
  i -= WTA_N;
  if (i < WC_N) {  // Wcat[n][kk]: kk<2048 Wf; <4096 Wb; else Wl
    const int n = i / KMRG, kk = i - n * KMRG;
    float v;
    if (kk < 2048) {
      const int r = kk >> 8, k = kk & 255;
      v = Wf[((size_t)r * 256 + k) * 256 + n];
    } else if (kk < 4096) {
      const int r = (kk - 2048) >> 8, k = kk & 255;
      v = Wb[((size_t)r * 256 + k) * 256 + n];
    } else {
      v = Wl[(size_t)(kk - 4096) * 256 + n];
    }
    Wcat[i] = f2bf(v);
    return;
  }
  i -= WC_N;
  if (i < NPAD) {
    cnt[i] = 0;
    return;
  }
  i -= NPAD;
  if (i < 256) zrow[i] = 0;
}

// ===========================================================================
// Edge bucketing: counting sort by (rel, endpoint), both directions.
// fwd key = r*N + dst (phase r); bwd key = (8+r)*N + src (phase 8+r).
// ===========================================================================
__global__ void hist_kernel(const int* __restrict__ src,
                            const int* __restrict__ dst,
                            const int* __restrict__ et, int* __restrict__ cnt) {
  int e = blockIdx.x * blockDim.x + threadIdx.x;
  if (e >= N_EDGES) return;
  int r = et[e];
  atomicAdd(&cnt[r * N_NODES + dst[e]], 1);
  atomicAdd(&cnt[(NUM_RELS + r) * N_NODES + src[e]], 1);
}

__global__ __launch_bounds__(256) void scan1_kernel(const int* __restrict__ cnt,
                                                    int* __restrict__ offs,
                                                    int* __restrict__ bsum) {
  __shared__ int s[256];
  const int b = blockIdx.x, t = threadIdx.x;
  const int base = b * SCAN_CHUNK + t * 4;
  int4 v = *reinterpret_cast<const int4*>(&cnt[base]);
  int tsum = v.x + v.y + v.z + v.w;
  s[t] = tsum;
  __syncthreads();
  for (int off = 1; off < 256; off <<= 1) {
    int x = (t >= off) ? s[t - off] : 0;
    __syncthreads();
    s[t] += x;
    __syncthreads();
  }
  int excl = s[t] - tsum;
  offs[base + 0] = excl;
  offs[base + 1] = excl + v.x;
  offs[base + 2] = excl + v.x + v.y;
  offs[base + 3] = excl + v.x + v.y + v.z;
  if (t == 0) bsum[b] = s[255];
}

__global__ __launch_bounds__(512) void scan2_kernel(int* __restrict__ bsum) {
  __shared__ int s[512];
  const int t = threadIdx.x;
  int v = (t < NCHUNK) ? bsum[t] : 0;
  s[t] = v;
  __syncthreads();
  for (int off = 1; off < 512; off <<= 1) {
    int x = (t >= off) ? s[t - off] : 0;
    __syncthreads();
    s[t] += x;
    __syncthreads();
  }
  if (t < NCHUNK) bsum[t] = s[t] - v;
}

__global__ void scan3_kernel(int* __restrict__ offs,
                             const int* __restrict__ bsum,
                             int* __restrict__ cur) {
  int i = blockIdx.x * blockDim.x + threadIdx.x;
  if (i >= NPAD) return;
  int v = offs[i] + bsum[i / SCAN_CHUNK];
  offs[i] = v;
  if (i < NBUCK) cur[i] = v;
}

__global__ void fill_kernel(const int* __restrict__ src,
                            const int* __restrict__ dst,
                            const int* __restrict__ et, int* __restrict__ cur,
                            int* __restrict__ gidx) {
  int e = blockIdx.x * blockDim.x + threadIdx.x;
  if (e >= N_EDGES) return;
  int r = et[e];
  int s = src[e], d = dst[e];
  int p1 = atomicAdd(&cur[r * N_NODES + d], 1);
  gidx[p1] = s;  // fwd: gather src, owner dst
  int p2 = atomicAdd(&cur[(NUM_RELS + r) * N_NODES + s], 1);
  gidx[p2] = d;  // bwd: gather dst, owner src
}

// is-multi flags (input to ordered-slot scan)
__global__ void mflag_kernel(const int* __restrict__ offs,
                             int* __restrict__ mflag) {
  int i = blockIdx.x * blockDim.x + threadIdx.x;
  if (i >= NPAD) return;
  mflag[i] = (i < NBUCK && offs[i + 1] - offs[i] >= 2) ? 1 : 0;
}

// rowptr[b]: empty -> ZROW; singleton -> XB0 + gather node (exact
// passthrough); multi -> ORDERED slot mslot[b] (prefix-scan order ->
// streaming A-reads in the GEMM; fixes round-8's random-slot poison).
__global__ void rowptr_kernel(const int* __restrict__ offs,
                              const int* __restrict__ gidx,
                              const int* __restrict__ mslot,
                              int* __restrict__ rowptr) {
  int b = blockIdx.x * blockDim.x + threadIdx.x;
  if (b >= NBUCK) return;
  int s = offs[b], e = offs[b + 1];
  int cnt = e - s;
  int rid;
  if (cnt == 0) rid = ZROW;
  else if (cnt == 1) rid = XB0 + gidx[s];
  else {
    int slot = mslot[b];
    if (slot > NZM - 1) slot = NZM - 1;  // 89-sigma-safe clamp
    rid = slot;
  }
  rowptr[b] = rid;
}

// ===========================================================================
// Affine GEMM (proven 128x128): xb[M,256] = bf16(fb[M,128] @ Wta^T + bias)
// ===========================================================================
__global__ __launch_bounds__(256) void gemm128_kernel(
    const unsigned short* __restrict__ A, int lda, int K,
    const unsigned short* __restrict__ Bt, const float* __restrict__ bias,
    unsigned short* __restrict__ Cb, int ldc, int M) {
  __shared__ __align__(16) unsigned short As[128 * 64];
  __shared__ __align__(16) unsigned short Bs[128 * 64];

  const int tid = threadIdx.x;
  const int lane = tid & 63;
  const int wave = tid >> 6;
  const int bm = blockIdx.y * 128;
  const int bn = blockIdx.x * 128;
  const int wr = wave >> 1;
  const int wc = wave & 1;
  const int g = lane >> 4;
  const int rl = lane & 15;

  f32x4 acc[4][4];
#pragma unroll
  for (int i = 0; i < 4; ++i)
#pragma unroll
    for (int j = 0; j < 4; ++j) acc[i][j] = (f32x4){0.f, 0.f, 0.f, 0.f};

  for (int k0 = 0; k0 < K; k0 += 64) {
#pragma unroll
    for (int c = 0; c < 8; ++c) {
      const int chunk = c * 4 + wave;
      if (chunk < 16) {
        const int S = chunk * 64 + lane;
        const int row = S >> 3;
        const int s = S & 7;
        int grow = bm + row;
        if (grow > M - 1) grow = M - 1;
        const int kcol = k0 + ((s ^ (row & 7)) << 3);
        const unsigned short* gp = A + (size_t)grow * lda + kcol;
        unsigned short* lp = As + (size_t)chunk * 512;
        __builtin_amdgcn_global_load_lds(
            (const __attribute__((address_space(1))) void*)gp,
            (__attribute__((address_space(3))) void*)lp, 16, 0, 0);
      } else {
        const int S = (chunk - 16) * 64 + lane;
        const int row = S >> 3;
        const int s = S & 7;
        const int kcol = k0 + ((s ^ (row & 7)) << 3);
        const unsigned short* gp = Bt + (size_t)(bn + row) * K + kcol;
        unsigned short* lp = Bs + (size_t)(chunk - 16) * 512;
        __builtin_amdgcn_global_load_lds(
            (const __attribute__((address_space(1))) void*)gp,
            (__attribute__((address_space(3))) void*)lp, 16, 0, 0);
      }
    }
    __syncthreads();

#pragma unroll
    for (int kk = 0; kk < 2; ++kk) {
      short8 a[4], b[4];
#pragma unroll
      for (int mi = 0; mi < 4; ++mi) {
        const int row = wr * 64 + mi * 16 + rl;
        const int slot = (kk * 4 + g) ^ (row & 7);
        a[mi] = *(const short8*)&As[row * 64 + slot * 8];
      }
#pragma unroll
      for (int ni = 0; ni < 4; ++ni) {
        const int row = wc * 64 + ni * 16 + rl;
        const int slot = (kk * 4 + g) ^ (row & 7);
        b[ni] = *(const short8*)&Bs[row * 64 + slot * 8];
      }
#pragma unroll
      for (int mi = 0; mi < 4; ++mi)
#pragma unroll
        for (int ni = 0; ni < 4; ++ni)
          acc[mi][ni] = __builtin_amdgcn_mfma_f32_16x16x32_bf16(
              a[mi], b[ni], acc[mi][ni], 0, 0, 0);
    }
    __syncthreads();
  }

#pragma unroll
  for (int mi = 0; mi < 4; ++mi) {
#pragma unroll
    for (int j = 0; j < 4; ++j) {
      const int row = bm + wr * 64 + mi * 16 + g * 4 + j;
      if (row >= M) continue;
#pragma unroll
      for (int ni = 0; ni < 4; ++ni) {
        const int col = bn + wc * 64 + ni * 16 + rl;
        Cb[(size_t)row * ldc + col] = f2bf(acc[mi][ni][j] + bias[col]);
      }
    }
  }
}

// ===========================================================================
// Merged z-gather: multi-edge buckets only, BOTH directions, one dispatch.
// Half-wave (32 lanes, 16 B/lane) per bucket; writes Zm row rowptr[b]
// (ordered slots). xb reads stay L2/L3-hot (only ~87 MB Zm written total).
// ===========================================================================
__global__ __launch_bounds__(256) void zgatherm_kernel(
    unsigned short* __restrict__ rowbase, const unsigned short* __restrict__ xb,
    const int* __restrict__ offs, const int* __restrict__ gidx,
    const int* __restrict__ rowptr) {
  const int lane = threadIdx.x & 63;
  const int hl = lane >> 5;
  const int l5 = lane & 31;
  const int b = blockIdx.x * 8 + (threadIdx.x >> 6) * 2 + hl;
  if (b >= NBUCK) return;
  const int s = offs[b], e = offs[b + 1];
  if (e - s < 2) return;  // empty/singleton resolved via rowptr indirection

  float acc[8] = {};
  for (int i = s; i < e; i += 4) {
    int g4[4];
    u16x8 xs[4];
#pragma unroll
    for (int q = 0; q < 4; ++q)
      if (i + q < e) g4[q] = gidx[i + q];
#pragma unroll
    for (int q = 0; q < 4; ++q)
      if (i + q < e)
        xs[q] = *(const u16x8*)&xb[(size_t)g4[q] * DDIM + l5 * 8];
#pragma unroll
    for (int q = 0; q < 4; ++q)
      if (i + q < e) {
#pragma unroll
        for (int j = 0; j < 8; ++j) acc[j] += bf2f((unsigned short)xs[q][j]);
      }
  }
  u16x8 o;
#pragma unroll
  for (int j = 0; j < 8; ++j) o[j] = (short)f2bf(acc[j]);
  *(u16x8*)&rowbase[(size_t)rowptr[b] * DDIM + l5 * 8] = o;
}

// ===========================================================================
// Virtual-A merged GEMM: h[M,256]+hbf = Avirt[M,4352] @ Wcat[256,4352]^T.
// A row for phase kb<16 via rowptr (ordered Zm / xb / zero row); kb==16
// reads xb. BM=64 x BN=128, 938 blocks, bijective XCD swizzle, plain stores.
// ===========================================================================
__global__ __launch_bounds__(256) void gemmv_kernel(
    const unsigned short* __restrict__ rowbase,
    const int* __restrict__ rowptr, const unsigned short* __restrict__ Bt,
    float* __restrict__ Cf, unsigned short* __restrict__ Cb, int M, int nblk) {
  __shared__ __align__(16) unsigned short As[64 * 64];   // 8 KB
  __shared__ __align__(16) unsigned short Bs[128 * 64];  // 16 KB

  const int tid = threadIdx.x;
  const int lane = tid & 63;
  const int wave = tid >> 6;

  // bijective XCD swizzle (nblk % 8 != 0 safe)
  const int orig = blockIdx.x;
  const int q = nblk >> 3, r = nblk & 7;
  const int xcd = orig & 7, off = orig >> 3;
  const int wg =
      (xcd < r) ? xcd * (q + 1) + off : r * (q + 1) + (xcd - r) * q + off;
  const int bm = (wg >> 1) * 64;
  const int bn = (wg & 1) * 128;

  const int wr = wave >> 1;  // 0..1: 32-row half
  const int wc = wave & 1;   // 0..1: 64-col half
  const int g = lane >> 4;
  const int rl = lane & 15;

  f32x4 acc[2][4];
#pragma unroll
  for (int i = 0; i < 2; ++i)
#pragma unroll
    for (int j = 0; j < 4; ++j) acc[i][j] = (f32x4){0.f, 0.f, 0.f, 0.f};

  for (int k0 = 0; k0 < KMRG; k0 += 64) {
    const int kb = k0 >> 8;      // phase 0..16
    const int koff = k0 & 255;   // col within 256-wide phase
#pragma unroll
    for (int c = 0; c < 6; ++c) {
      const int chunk = c * 4 + wave;
      if (chunk < 8) {
        const int S = chunk * 64 + lane;
        const int row = S >> 3;  // 0..63
        const int s = S & 7;
        int node = bm + row;
        if (node > M - 1) node = M - 1;
        const int rid =
            (kb < 16) ? rowptr[kb * N_NODES + node] : (XB0 + node);
        const unsigned short* gp =
            rowbase + (size_t)rid * 256 + koff + ((s ^ (row & 7)) << 3);
        unsigned short* lp = As + (size_t)chunk * 512;
        __builtin_amdgcn_global_load_lds(
            (const __attribute__((address_space(1))) void*)gp,
            (__attribute__((address_space(3))) void*)lp, 16, 0, 0);
      } else {
        const int S = (chunk - 8) * 64 + lane;
        const int row = S >> 3;  // 0..127
        const int s = S & 7;
        const unsigned short* gp =
            Bt + (size_t)(bn + row) * KMRG + k0 + ((s ^ (row & 7)) << 3);
        unsigned short* lp = Bs + (size_t)(chunk - 8) * 512;
        __builtin_amdgcn_global_load_lds(
            (const __attribute__((address_space(1))) void*)gp,
            (__attribute__((address_space(3))) void*)lp, 16, 0, 0);
      }
    }
    __syncthreads();

#pragma unroll
    for (int kk = 0; kk < 2; ++kk) {
      short8 a[2], b[4];
#pragma unroll
      for (int mi = 0; mi < 2; ++mi) {
        const int row = wr * 32 + mi * 16 + rl;
        const int slot = (kk * 4 + g) ^ (row & 7);
        a[mi] = *(const short8*)&As[row * 64 + slot * 8];
      }
#pragma unroll
      for (int ni = 0; ni < 4; ++ni) {
        const int row = wc * 64 + ni * 16 + rl;
        const int slot = (kk * 4 + g) ^ (row & 7);
        b[ni] = *(const short8*)&Bs[row * 64 + slot * 8];
      }
#pragma unroll
      for (int mi = 0; mi < 2; ++mi)
#pragma unroll
        for (int ni = 0; ni < 4; ++ni)
          acc[mi][ni] = __builtin_amdgcn_mfma_f32_16x16x32_bf16(
              a[mi], b[ni], acc[mi][ni], 0, 0, 0);
    }
    __syncthreads();
  }

#pragma unroll
  for (int mi = 0; mi < 2; ++mi) {
#pragma unroll
    for (int j = 0; j < 4; ++j) {
      const int row = bm + wr * 32 + mi * 16 + g * 4 + j;
      if (row >= M) continue;
#pragma unroll
      for (int ni = 0; ni < 4; ++ni) {
        const int col = bn + wc * 64 + ni * 16 + rl;
        const float v = acc[mi][ni][j];
        const size_t idx = (size_t)row * DDIM + col;
        Cf[idx] = v;
        Cb[idx] = f2bf(v);
      }
    }
  }
}

// ===========================================================================
// DistMult scoring (32-lane rows, bf16 h).
// ===========================================================================
__global__ __launch_bounds__(256) void score32_kernel(
    const unsigned short* __restrict__ hb, const float* __restrict__ wrel,
    const int* __restrict__ ts, const int* __restrict__ tr,
    const int* __restrict__ to, float* __restrict__ out, int T) {
  const int t = blockIdx.x * 8 + (threadIdx.x >> 5);
  if (t >= T) return;
  const int l5 = threadIdx.x & 31;
  const int s = ts[t];
  const int r = tr[t];
  const int o = to[t];
  const u16x8 hs = *(const u16x8*)&hb[(size_t)s * DDIM + l5 * 8];
  const u16x8 ho = *(const u16x8*)&hb[(size_t)o * DDIM + l5 * 8];
  const float4 w0 = *(const float4*)&wrel[(size_t)r * DDIM + l5 * 8];
  const float4 w1 = *(const float4*)&wrel[(size_t)r * DDIM + l5 * 8 + 4];
  float sum = bf2f((unsigned short)hs[0]) * w0.x * bf2f((unsigned short)ho[0]) +
              bf2f((unsigned short)hs[1]) * w0.y * bf2f((unsigned short)ho[1]) +
              bf2f((unsigned short)hs[2]) * w0.z * bf2f((unsigned short)ho[2]) +
              bf2f((unsigned short)hs[3]) * w0.w * bf2f((unsigned short)ho[3]) +
              bf2f((unsigned short)hs[4]) * w1.x * bf2f((unsigned short)ho[4]) +
              bf2f((unsigned short)hs[5]) * w1.y * bf2f((unsigned short)ho[5]) +
              bf2f((unsigned short)hs[6]) * w1.z * bf2f((unsigned short)ho[6]) +
              bf2f((unsigned short)hs[7]) * w1.w * bf2f((unsigned short)ho[7]);
#pragma unroll
  for (int off = 16; off; off >>= 1) sum += __shfl_down(sum, off, 32);
  if (l5 == 0) out[t] = sum;
}

// ===========================================================================
extern "C" void kernel_launch(void* const* d_in, const int* in_sizes, int n_in,
                              void* d_out, int out_size, void* d_ws,
                              size_t ws_size, hipStream_t stream) {
  const float* feats = (const float*)d_in[0];
  const float* W_affine = (const float*)d_in[1];
  const float* b_affine = (const float*)d_in[2];
  const float* W_fwd = (const float*)d_in[3];
  const float* W_bwd = (const float*)d_in[4];
  const float* W_loop = (const float*)d_in[5];
  const float* w_relation = (const float*)d_in[6];
  const int* src = (const int*)d_in[7];
  const int* dst = (const int*)d_in[8];
  const int* etype = (const int*)d_in[9];
  const int* trip_s = (const int*)d_in[10];
  const int* trip_r = (const int*)d_in[11];
  const int* trip_o = (const int*)d_in[12];

  float* out_w = (float*)d_out;  // [N_TRIP]
  float* h = out_w + N_TRIP;     // [N_NODES * D] fp32

  // ---- workspace layout (~147.5 MB; 172 MB proven available) ----
  // Row-id space (512 B rows from ws base): [0,NZM) Zm ordered slots;
  // [XB0, XB0+30000) xb; ZROW zero row. fb aliases Zm head (freed before
  // zgatherm writes Zm).
  char* ws = (char*)d_ws;
  unsigned short* rowbase = (unsigned short*)ws;
  unsigned short* fb = (unsigned short*)ws;                   // alias Zm head
  unsigned short* xb = rowbase + (size_t)XB0 * 256;           // 102,400,000
  unsigned short* zrow = rowbase + (size_t)ZROW * 256;        // 117,760,000
  unsigned short* hbf = (unsigned short*)(ws + 117760512);    // 15,360,000
  int* offs = (int*)(ws + 133120512);                         // 1,921,024
  int* cnt = (int*)(ws + 135041536);                          // 1,921,024
  int* cur = (int*)(ws + 136962560);                          // 1,921,024
  int* bsum = (int*)(ws + 138883584);                         // 2,048
  int* gidx = (int*)(ws + 138885632);                         // 2,400,000
  int* mslot = (int*)(ws + 141285632);                        // 1,921,024
  int* rowptr = (int*)(ws + 143206656);                       // 1,920,000
  unsigned short* Wta = (unsigned short*)(ws + 145126656);    // 65,536
  unsigned short* Wcat = (unsigned short*)(ws + 145192192);   // 2,228,224

  // ---- fused prep ----
  prep_kernel<<<(PREP_TOTAL + 255) / 256, 256, 0, stream>>>(
      feats, W_affine, W_fwd, W_bwd, W_loop, fb, Wta, Wcat, cnt, zrow);

  // ---- edge bucketing ----
  hist_kernel<<<(N_EDGES + 255) / 256, 256, 0, stream>>>(src, dst, etype, cnt);
  scan1_kernel<<<NCHUNK, 256, 0, stream>>>(cnt, offs, bsum);
  scan2_kernel<<<1, 512, 0, stream>>>(bsum);
  scan3_kernel<<<(NPAD + 255) / 256, 256, 0, stream>>>(offs, bsum, cur);
  fill_kernel<<<(N_EDGES + 255) / 256, 256, 0, stream>>>(src, dst, etype, cur,
                                                         gidx);

  // ---- ordered multi-slot scan + rowptr ----
  mflag_kernel<<<(NPAD + 255) / 256, 256, 0, stream>>>(offs, cnt);
  scan1_kernel<<<NCHUNK, 256, 0, stream>>>(cnt, mslot, bsum);
  scan2_kernel<<<1, 512, 0, stream>>>(bsum);
  scan3_kernel<<<(NPAD + 255) / 256, 256, 0, stream>>>(mslot, bsum, cur);
  rowptr_kernel<<<(NBUCK + 255) / 256, 256, 0, stream>>>(offs, gidx, mslot,
                                                         rowptr);

  // ---- xb = bf16(feats @ W_affine + b)  (reads fb before Zm overwrite) ----
  const dim3 agrid(2, (N_NODES + 127) / 128);
  gemm128_kernel<<<agrid, 256, 0, stream>>>(fb, F_RAW, F_RAW, Wta, b_affine,
                                            xb, DDIM, N_NODES);

  // ---- multi-bucket sums (both directions, one dispatch) ----
  zgatherm_kernel<<<(NBUCK + 7) / 8, 256, 0, stream>>>(rowbase, xb, offs, gidx,
                                                       rowptr);

  // ---- merged virtual-A GEMM: h + hbf in one pass ----
  const int nblk = 2 * ((N_NODES + 63) / 64);  // 938
  gemmv_kernel<<<nblk, 256, 0, stream>>>(rowbase, rowptr, Wcat, h, hbf,
                                         N_NODES, nblk);

  // ---- DistMult scoring ----
  score32_kernel<<<(N_TRIP + 7) / 8, 256, 0, stream>>>(
      hbf, w_relation, trip_s, trip_r, trip_o, out_w, N_TRIP);
}

// Round 15
// 289.044 us; speedup vs baseline: 1.1064x; 1.0284x over previous
//
#include <hip/hip_runtime.h>

#define N_NODES 30000
#define N_EDGES 300000
#define N_TRIP 200000
#define NUM_RELS 8
#define F_RAW 128
#define DDIM 256

#define NBUCK (2 * NUM_RELS * N_NODES)                    // 480000 buckets
#define SCAN_CHUNK 1024
#define NCHUNK ((NBUCK + SCAN_CHUNK - 1) / SCAN_CHUNK)    // 469
#define NPAD (NCHUNK * SCAN_CHUNK)                        // 480256

#define KBIG 2304   // 8 rel blocks + x block
#define KBWD 2048   // 8 rel blocks

// fused-prep segment sizes
#define FB_N (N_NODES * F_RAW)   // 3,840,000
#define WTA_N (F_RAW * DDIM)     // 32,768
#define WC1_N (256 * KBIG)       // 589,824
#define WC2_N (256 * KBWD)       // 524,288
#define PREP_TOTAL (FB_N + WTA_N + WC1_N + WC2_N + NPAD)

typedef __attribute__((ext_vector_type(8))) short short8;
typedef __attribute__((ext_vector_type(8))) unsigned short u16x8;
typedef __attribute__((ext_vector_type(4))) float f32x4;

__device__ inline unsigned short f2bf(float f) {
  unsigned u = __builtin_bit_cast(unsigned, f);
  u = (u + 0x7FFFu + ((u >> 16) & 1u)) >> 16;
  return (unsigned short)u;
}
__device__ inline float bf2f(unsigned short s) {
  unsigned u = ((unsigned)s) << 16;
  return __builtin_bit_cast(float, u);
}

// ===========================================================================
// Fused prep: feats->bf16, Wta transpose, Wcat1/Wcat2 build, cnt zero.
// One dispatch, disjoint flat-index segments.
// ===========================================================================
__global__ void prep_kernel(const float* __restrict__ feats,
                            const float* __restrict__ W_affine,
                            const float* __restrict__ Wf,
                            const float* __restrict__ Wb,
                            const float* __restrict__ Wl,
                            unsigned short* __restrict__ fb,
                            unsigned short* __restrict__ Wta,
                            unsigned short* __restrict__ Wcat1,
                            unsigned short* __restrict__ Wcat2,
                            int* __restrict__ cnt) {
  int i = blockIdx.x * blockDim.x + threadIdx.x;
  if (i < FB_N) {
    fb[i] = f2bf(feats[i]);
    return;
  }
  i -= FB_N;
  if (i < WTA_N) {  // Wta[n][k] = W_affine[k][n]
    const int n = i >> 7, k = i & 127;
    Wta[i] = f2bf(W_affine[(size_t)k * DDIM + n]);
    return;
  }
  i -= WTA_N;
  if (i < WC1_N) {  // Wcat1[n][kk]: kk<2048 Wf[kk>>8][kk&255][n] else Wl
    const int n = i / KBIG, kk = i - n * KBIG;
    float v;
    if (kk < 2048) {
      const int r = kk >> 8, k = kk & 255;
      v = Wf[((size_t)r * 256 + k) * 256 + n];
    } else {
      v = Wl[(size_t)(kk - 2048) * 256 + n];
    }
    Wcat1[i] = f2bf(v);
    return;
  }
  i -= WC1_N;
  if (i < WC2_N) {  // Wcat2[n][kk] = Wb[kk>>8][kk&255][n]
    const int n = i / KBWD, kk = i - n * KBWD;
    const int r = kk >> 8, k = kk & 255;
    Wcat2[i] = f2bf(Wb[((size_t)r * 256 + k) * 256 + n]);
    return;
  }
  i -= WC2_N;
  if (i < NPAD) cnt[i] = 0;
}

// ===========================================================================
// Edge bucketing: counting sort by (rel, endpoint), both directions.
// fwd key = r*N + dst; bwd key = (8+r)*N + src. gidx[pos] = gather-node.
// ===========================================================================
__global__ void hist_kernel(const int* __restrict__ src,
                            const int* __restrict__ dst,
                            const int* __restrict__ et, int* __restrict__ cnt) {
  int e = blockIdx.x * blockDim.x + threadIdx.x;
  if (e >= N_EDGES) return;
  int r = et[e];
  atomicAdd(&cnt[r * N_NODES + dst[e]], 1);
  atomicAdd(&cnt[(NUM_RELS + r) * N_NODES + src[e]], 1);
}

__global__ __launch_bounds__(256) void scan1_kernel(const int* __restrict__ cnt,
                                                    int* __restrict__ offs,
                                                    int* __restrict__ bsum) {
  __shared__ int s[256];
  const int b = blockIdx.x, t = threadIdx.x;
  const int base = b * SCAN_CHUNK + t * 4;
  int4 v = *reinterpret_cast<const int4*>(&cnt[base]);
  int tsum = v.x + v.y + v.z + v.w;
  s[t] = tsum;
  __syncthreads();
  for (int off = 1; off < 256; off <<= 1) {
    int x = (t >= off) ? s[t - off] : 0;
    __syncthreads();
    s[t] += x;
    __syncthreads();
  }
  int excl = s[t] - tsum;
  offs[base + 0] = excl;
  offs[base + 1] = excl + v.x;
  offs[base + 2] = excl + v.x + v.y;
  offs[base + 3] = excl + v.x + v.y + v.z;
  if (t == 0) bsum[b] = s[255];
}

__global__ __launch_bounds__(512) void scan2_kernel(int* __restrict__ bsum) {
  __shared__ int s[512];
  const int t = threadIdx.x;
  int v = (t < NCHUNK) ? bsum[t] : 0;
  s[t] = v;
  __syncthreads();
  for (int off = 1; off < 512; off <<= 1) {
    int x = (t >= off) ? s[t - off] : 0;
    __syncthreads();
    s[t] += x;
    __syncthreads();
  }
  if (t < NCHUNK) bsum[t] = s[t] - v;
}

__global__ void scan3_kernel(int* __restrict__ offs,
                             const int* __restrict__ bsum,
                             int* __restrict__ cur) {
  int i = blockIdx.x * blockDim.x + threadIdx.x;
  if (i >= NPAD) return;
  int v = offs[i] + bsum[i / SCAN_CHUNK];
  offs[i] = v;
  if (i < NBUCK) cur[i] = v;
}

__global__ void fill_kernel(const int* __restrict__ src,
                            const int* __restrict__ dst,
                            const int* __restrict__ et, int* __restrict__ cur,
                            int* __restrict__ gidx) {
  int e = blockIdx.x * blockDim.x + threadIdx.x;
  if (e >= N_EDGES) return;
  int r = et[e];
  int s = src[e], d = dst[e];
  int p1 = atomicAdd(&cur[r * N_NODES + d], 1);
  gidx[p1] = s;  // fwd: gather src, owner dst
  int p2 = atomicAdd(&cur[(NUM_RELS + r) * N_NODES + s], 1);
  gidx[p2] = d;  // bwd: gather dst, owner src
}

// ===========================================================================
// Affine GEMM (proven 128x128): C_bf16[M, ldc] = A[M,lda(K)] @ Bt[256,K]^T + b
// ===========================================================================
__global__ __launch_bounds__(256) void gemm128_kernel(
    const unsigned short* __restrict__ A, int lda, int K,
    const unsigned short* __restrict__ Bt, const float* __restrict__ bias,
    unsigned short* __restrict__ Cb, int ldc, int M) {
  __shared__ __align__(16) unsigned short As[128 * 64];
  __shared__ __align__(16) unsigned short Bs[128 * 64];

  const int tid = threadIdx.x;
  const int lane = tid & 63;
  const int wave = tid >> 6;
  const int bm = blockIdx.y * 128;
  const int bn = blockIdx.x * 128;
  const int wr = wave >> 1;
  const int wc = wave & 1;
  const int g = lane >> 4;
  const int rl = lane & 15;

  f32x4 acc[4][4];
#pragma unroll
  for (int i = 0; i < 4; ++i)
#pragma unroll
    for (int j = 0; j < 4; ++j) acc[i][j] = (f32x4){0.f, 0.f, 0.f, 0.f};

  for (int k0 = 0; k0 < K; k0 += 64) {
#pragma unroll
    for (int c = 0; c < 8; ++c) {
      const int chunk = c * 4 + wave;
      if (chunk < 16) {
        const int S = chunk * 64 + lane;
        const int row = S >> 3;
        const int s = S & 7;
        int grow = bm + row;
        if (grow > M - 1) grow = M - 1;
        const int kcol = k0 + ((s ^ (row & 7)) << 3);
        const unsigned short* gp = A + (size_t)grow * lda + kcol;
        unsigned short* lp = As + (size_t)chunk * 512;
        __builtin_amdgcn_global_load_lds(
            (const __attribute__((address_space(1))) void*)gp,
            (__attribute__((address_space(3))) void*)lp, 16, 0, 0);
      } else {
        const int S = (chunk - 16) * 64 + lane;
        const int row = S >> 3;
        const int s = S & 7;
        const int kcol = k0 + ((s ^ (row & 7)) << 3);
        const unsigned short* gp = Bt + (size_t)(bn + row) * K + kcol;
        unsigned short* lp = Bs + (size_t)(chunk - 16) * 512;
        __builtin_amdgcn_global_load_lds(
            (const __attribute__((address_space(1))) void*)gp,
            (__attribute__((address_space(3))) void*)lp, 16, 0, 0);
      }
    }
    __syncthreads();

#pragma unroll
    for (int kk = 0; kk < 2; ++kk) {
      short8 a[4], b[4];
#pragma unroll
      for (int mi = 0; mi < 4; ++mi) {
        const int row = wr * 64 + mi * 16 + rl;
        const int slot = (kk * 4 + g) ^ (row & 7);
        a[mi] = *(const short8*)&As[row * 64 + slot * 8];
      }
#pragma unroll
      for (int ni = 0; ni < 4; ++ni) {
        const int row = wc * 64 + ni * 16 + rl;
        const int slot = (kk * 4 + g) ^ (row & 7);
        b[ni] = *(const short8*)&Bs[row * 64 + slot * 8];
      }
#pragma unroll
      for (int mi = 0; mi < 4; ++mi)
#pragma unroll
        for (int ni = 0; ni < 4; ++ni)
          acc[mi][ni] = __builtin_amdgcn_mfma_f32_16x16x32_bf16(
              a[mi], b[ni], acc[mi][ni], 0, 0, 0);
    }
    __syncthreads();
  }

#pragma unroll
  for (int mi = 0; mi < 4; ++mi) {
#pragma unroll
    for (int j = 0; j < 4; ++j) {
      const int row = bm + wr * 64 + mi * 16 + g * 4 + j;
      if (row >= M) continue;
#pragma unroll
      for (int ni = 0; ni < 4; ++ni) {
        const int col = bn + wc * 64 + ni * 16 + rl;
        Cb[(size_t)row * ldc + col] = f2bf(acc[mi][ni][j] + bias[col]);
      }
    }
  }
}

// ===========================================================================
// Wide-K GEMM, BM=64 x BN=128 (proven best config): 938 blocks, 24 KB LDS,
// bijective XCD swizzle, plain stores. C[M,256] = A[M,K(lda)] @ Bt[256,K]^T.
// OUT_MODE: 0 = write f32; 2 = f32-RMW + bf16 copy.
// Ledger: beats {128x128, 32x128, K-split-atomic, virtual-A(x2), NT, dbuf}.
// ===========================================================================
template <int OUT_MODE>
__global__ __launch_bounds__(256) void gemm64_kernel(
    const unsigned short* __restrict__ A, int lda, int K,
    const unsigned short* __restrict__ Bt, float* __restrict__ Cf,
    unsigned short* __restrict__ Cb, int ldc, int M, int nblk) {
  __shared__ __align__(16) unsigned short As[64 * 64];   // 8 KB
  __shared__ __align__(16) unsigned short Bs[128 * 64];  // 16 KB

  const int tid = threadIdx.x;
  const int lane = tid & 63;
  const int wave = tid >> 6;

  // bijective XCD swizzle (nblk % 8 != 0 safe)
  const int orig = blockIdx.x;
  const int q = nblk >> 3, r = nblk & 7;
  const int xcd = orig & 7, off = orig >> 3;
  const int wg =
      (xcd < r) ? xcd * (q + 1) + off : r * (q + 1) + (xcd - r) * q + off;
  const int bm = (wg >> 1) * 64;
  const int bn = (wg & 1) * 128;

  const int wr = wave >> 1;  // 0..1: 32-row half
  const int wc = wave & 1;   // 0..1: 64-col half
  const int g = lane >> 4;
  const int rl = lane & 15;

  f32x4 acc[2][4];
#pragma unroll
  for (int i = 0; i < 2; ++i)
#pragma unroll
    for (int j = 0; j < 4; ++j) acc[i][j] = (f32x4){0.f, 0.f, 0.f, 0.f};

  for (int k0 = 0; k0 < K; k0 += 64) {
    // stage A (8 x 1KB) + B (16 x 1KB): 6 chunks per wave
#pragma unroll
    for (int c = 0; c < 6; ++c) {
      const int chunk = c * 4 + wave;
      if (chunk < 8) {
        const int S = chunk * 64 + lane;
        const int row = S >> 3;  // 0..63
        const int s = S & 7;
        int grow = bm + row;
        if (grow > M - 1) grow = M - 1;
        const unsigned short* gp =
            A + (size_t)grow * lda + k0 + ((s ^ (row & 7)) << 3);
        unsigned short* lp = As + (size_t)chunk * 512;
        __builtin_amdgcn_global_load_lds(
            (const __attribute__((address_space(1))) void*)gp,
            (__attribute__((address_space(3))) void*)lp, 16, 0, 0);
      } else {
        const int S = (chunk - 8) * 64 + lane;
        const int row = S >> 3;  // 0..127
        const int s = S & 7;
        const unsigned short* gp =
            Bt + (size_t)(bn + row) * K + k0 + ((s ^ (row & 7)) << 3);
        unsigned short* lp = Bs + (size_t)(chunk - 8) * 512;
        __builtin_amdgcn_global_load_lds(
            (const __attribute__((address_space(1))) void*)gp,
            (__attribute__((address_space(3))) void*)lp, 16, 0, 0);
      }
    }
    __syncthreads();

#pragma unroll
    for (int kk = 0; kk < 2; ++kk) {
      short8 a[2], b[4];
#pragma unroll
      for (int mi = 0; mi < 2; ++mi) {
        const int row = wr * 32 + mi * 16 + rl;
        const int slot = (kk * 4 + g) ^ (row & 7);
        a[mi] = *(const short8*)&As[row * 64 + slot * 8];
      }
#pragma unroll
      for (int ni = 0; ni < 4; ++ni) {
        const int row = wc * 64 + ni * 16 + rl;
        const int slot = (kk * 4 + g) ^ (row & 7);
        b[ni] = *(const short8*)&Bs[row * 64 + slot * 8];
      }
#pragma unroll
      for (int mi = 0; mi < 2; ++mi)
#pragma unroll
        for (int ni = 0; ni < 4; ++ni)
          acc[mi][ni] = __builtin_amdgcn_mfma_f32_16x16x32_bf16(
              a[mi], b[ni], acc[mi][ni], 0, 0, 0);
    }
    __syncthreads();
  }

#pragma unroll
  for (int mi = 0; mi < 2; ++mi) {
#pragma unroll
    for (int j = 0; j < 4; ++j) {
      const int row = bm + wr * 32 + mi * 16 + g * 4 + j;
      if (row >= M) continue;
#pragma unroll
      for (int ni = 0; ni < 4; ++ni) {
        const int col = bn + wc * 64 + ni * 16 + rl;
        float v = acc[mi][ni][j];
        const size_t idx = (size_t)row * ldc + col;
        if (OUT_MODE == 0) {
          Cf[idx] = v;
        } else {
          v += Cf[idx];
          Cf[idx] = v;
          Cb[idx] = f2bf(v);
        }
      }
    }
  }
}

// ===========================================================================
// z-gather (32-lane rows): 2 buckets per wave, 16 B/lane loads, 4-deep batch.
// ===========================================================================
__global__ __launch_bounds__(256) void zgatherw_kernel(
    unsigned short* __restrict__ Z, int colbase,
    const int* __restrict__ offs_base, const int* __restrict__ gidx) {
  const int lane = threadIdx.x & 63;
  const int hl = lane >> 5;
  const int l5 = lane & 31;
  const int b = blockIdx.x * 8 + (threadIdx.x >> 6) * 2 + hl;
  if (b >= NUM_RELS * N_NODES) return;
  const int r = b / N_NODES;
  const int v = b - r * N_NODES;
  const int s = offs_base[b], e = offs_base[b + 1];

  float acc[8] = {};
  for (int i = s; i < e; i += 4) {
    int g4[4];
    u16x8 xs[4];
#pragma unroll
    for (int q = 0; q < 4; ++q)
      if (i + q < e) g4[q] = gidx[i + q];
#pragma unroll
    for (int q = 0; q < 4; ++q)
      if (i + q < e)
        xs[q] = *(const u16x8*)&Z[(size_t)g4[q] * KBIG + 2048 + l5 * 8];
#pragma unroll
    for (int q = 0; q < 4; ++q)
      if (i + q < e) {
#pragma unroll
        for (int j = 0; j < 8; ++j) acc[j] += bf2f((unsigned short)xs[q][j]);
      }
  }
  u16x8 o;
#pragma unroll
  for (int j = 0; j < 8; ++j) o[j] = (short)f2bf(acc[j]);
  *(u16x8*)&Z[(size_t)v * KBIG + colbase + r * 256 + l5 * 8] = o;
}

// ===========================================================================
// DistMult scoring (32-lane rows, bf16 h).
// ===========================================================================
__global__ __launch_bounds__(256) void score32_kernel(
    const unsigned short* __restrict__ hb, const float* __restrict__ wrel,
    const int* __restrict__ ts, const int* __restrict__ tr,
    const int* __restrict__ to, float* __restrict__ out, int T) {
  const int t = blockIdx.x * 8 + (threadIdx.x >> 5);
  if (t >= T) return;
  const int l5 = threadIdx.x & 31;
  const int s = ts[t];
  const int r = tr[t];
  const int o = to[t];
  const u16x8 hs = *(const u16x8*)&hb[(size_t)s * DDIM + l5 * 8];
  const u16x8 ho = *(const u16x8*)&hb[(size_t)o * DDIM + l5 * 8];
  const float4 w0 = *(const float4*)&wrel[(size_t)r * DDIM + l5 * 8];
  const float4 w1 = *(const float4*)&wrel[(size_t)r * DDIM + l5 * 8 + 4];
  float sum = bf2f((unsigned short)hs[0]) * w0.x * bf2f((unsigned short)ho[0]) +
              bf2f((unsigned short)hs[1]) * w0.y * bf2f((unsigned short)ho[1]) +
              bf2f((unsigned short)hs[2]) * w0.z * bf2f((unsigned short)ho[2]) +
              bf2f((unsigned short)hs[3]) * w0.w * bf2f((unsigned short)ho[3]) +
              bf2f((unsigned short)hs[4]) * w1.x * bf2f((unsigned short)ho[4]) +
              bf2f((unsigned short)hs[5]) * w1.y * bf2f((unsigned short)ho[5]) +
              bf2f((unsigned short)hs[6]) * w1.z * bf2f((unsigned short)ho[6]) +
              bf2f((unsigned short)hs[7]) * w1.w * bf2f((unsigned short)ho[7]);
#pragma unroll
  for (int off = 16; off; off >>= 1) sum += __shfl_down(sum, off, 32);
  if (l5 == 0) out[t] = sum;
}

// ===========================================================================
extern "C" void kernel_launch(void* const* d_in, const int* in_sizes, int n_in,
                              void* d_out, int out_size, void* d_ws,
                              size_t ws_size, hipStream_t stream) {
  const float* feats = (const float*)d_in[0];
  const float* W_affine = (const float*)d_in[1];
  const float* b_affine = (const float*)d_in[2];
  const float* W_fwd = (const float*)d_in[3];
  const float* W_bwd = (const float*)d_in[4];
  const float* W_loop = (const float*)d_in[5];
  const float* w_relation = (const float*)d_in[6];
  const int* src = (const int*)d_in[7];
  const int* dst = (const int*)d_in[8];
  const int* etype = (const int*)d_in[9];
  const int* trip_s = (const int*)d_in[10];
  const int* trip_r = (const int*)d_in[11];
  const int* trip_o = (const int*)d_in[12];

  float* out_w = (float*)d_out;  // [N_TRIP]
  float* h = out_w + N_TRIP;     // [N_NODES * D] fp32

  char* ws = (char*)d_ws;
  unsigned short* fb = (unsigned short*)(ws);                 // 7,680,000
  unsigned short* Z = (unsigned short*)(ws + 7680000);        // 138,240,000
  unsigned short* hbf = (unsigned short*)(ws + 145920000);    // 15,360,000
  unsigned short* Wta = (unsigned short*)(ws + 161280000);    // 65,536
  unsigned short* Wcat1 = (unsigned short*)(ws + 161345536);  // 1,179,648
  unsigned short* Wcat2 = (unsigned short*)(ws + 162525184);  // 1,048,576
  int* cnt = (int*)(ws + 163573760);                          // 1,921,024
  int* offs = (int*)(ws + 165494784);                         // 1,921,024
  int* cur = (int*)(ws + 167415808);                          // 1,921,024
  int* bsum = (int*)(ws + 169336832);                         // 2,048
  int* gidx = (int*)(ws + 169338880);                         // 2,400,000

  // ---- fused prep (conversions + weight builds + cnt zero) ----
  prep_kernel<<<(PREP_TOTAL + 255) / 256, 256, 0, stream>>>(
      feats, W_affine, W_fwd, W_bwd, W_loop, fb, Wta, Wcat1, Wcat2, cnt);

  // ---- edge bucketing ----
  hist_kernel<<<(N_EDGES + 255) / 256, 256, 0, stream>>>(src, dst, etype, cnt);
  scan1_kernel<<<NCHUNK, 256, 0, stream>>>(cnt, offs, bsum);
  scan2_kernel<<<1, 512, 0, stream>>>(bsum);
  scan3_kernel<<<(NPAD + 255) / 256, 256, 0, stream>>>(offs, bsum, cur);
  fill_kernel<<<(N_EDGES + 255) / 256, 256, 0, stream>>>(src, dst, etype, cur,
                                                         gidx);

  // ---- x -> Z cols [2048, 2304) ----
  const dim3 agrid(2, (N_NODES + 127) / 128);
  gemm128_kernel<<<agrid, 256, 0, stream>>>(fb, F_RAW, F_RAW, Wta, b_affine,
                                            Z + 2048, KBIG, N_NODES);

  const int nblk = 2 * ((N_NODES + 63) / 64);  // 938
  const int zgrid = (NUM_RELS * N_NODES + 7) / 8;

  // ---- Z_fwd cols [0,2048); h = [Z_fwd | x] @ [Wf ; Wl] ----
  zgatherw_kernel<<<zgrid, 256, 0, stream>>>(Z, 0, offs, gidx);
  gemm64_kernel<0><<<nblk, 256, 0, stream>>>(Z, KBIG, KBIG, Wcat1, h, nullptr,
                                             DDIM, N_NODES, nblk);
  // ---- Z_bwd overwrites cols [0,2048); h += Z_bwd @ [Wb], emit hbf ----
  zgatherw_kernel<<<zgrid, 256, 0, stream>>>(Z, 0, offs + NUM_RELS * N_NODES,
                                             gidx);
  gemm64_kernel<2><<<nblk, 256, 0, stream>>>(Z, KBIG, KBWD, Wcat2, h, hbf,
                                             DDIM, N_NODES, nblk);

  // ---- DistMult scoring ----
  score32_kernel<<<(N_TRIP + 7) / 8, 256, 0, stream>>>(
      hbf, w_relation, trip_s, trip_r, trip_o, out_w, N_TRIP);
}